// Round 1
// baseline (60.718 us; speedup 1.0000x reference)
//
#include <hip/hip_runtime.h>

constexpr int NW     = 12;        // wires
constexpr int NS     = 1 << NW;   // 4096 states
constexpr int BLOCK  = 256;
constexpr int NLAYER = 2;

// Insert a 0-bit at the position given by single-bit `mask`.
__device__ __forceinline__ int insert0(int v, int mask) {
    return ((v & ~(mask - 1)) << 1) | (v & (mask - 1));
}

__global__ __launch_bounds__(BLOCK)
void qnn_kernel(const float* __restrict__ x,     // [B,12]
                const float* __restrict__ var,   // [2,12,3]
                const float* __restrict__ hw,    // [12]
                const float* __restrict__ hb,    // [1]
                float* __restrict__ out)         // [B]
{
    __shared__ float sre[NS];
    __shared__ float sim[NS];
    __shared__ float wavesum[BLOCK / 64];

    const int b = blockIdx.x;
    const int t = threadIdx.x;

    // |0...0> init
    #pragma unroll
    for (int k = 0; k < NS / BLOCK; ++k) {
        int i = t + k * BLOCK;
        sre[i] = (i == 0) ? 1.0f : 0.0f;
        sim[i] = 0.0f;
    }
    __syncthreads();

    // ---- RY(x[b,w]) encoding: real 2x2 [[c,-s],[s,c]], c=cos(x/2) ----
    for (int w = 0; w < NW; ++w) {
        float sn, cs;
        sincosf(0.5f * x[b * NW + w], &sn, &cs);
        const int post = 1 << (NW - 1 - w);
        #pragma unroll
        for (int k = 0; k < (NS / 2) / BLOCK; ++k) {
            int p  = t + k * BLOCK;
            int i0 = insert0(p, post);
            int i1 = i0 + post;
            float r0 = sre[i0], m0 = sim[i0];
            float r1 = sre[i1], m1 = sim[i1];
            sre[i0] = cs * r0 - sn * r1;
            sim[i0] = cs * m0 - sn * m1;
            sre[i1] = sn * r0 + cs * r1;
            sim[i1] = sn * m0 + cs * m1;
        }
        __syncthreads();
    }

    // ---- StronglyEntanglingLayers ----
    for (int l = 0; l < NLAYER; ++l) {
        // Rot(phi,theta,omega) = RZ(omega) RY(theta) RZ(phi), shared across batch
        for (int w = 0; w < NW; ++w) {
            const float phi   = var[(l * NW + w) * 3 + 0];
            const float theta = var[(l * NW + w) * 3 + 1];
            const float omega = var[(l * NW + w) * 3 + 2];
            float st, ct;  sincosf(0.5f * theta, &st, &ct);
            float sp, cp;  sincosf(-0.5f * (phi + omega), &sp, &cp);  // ep = cp + i sp
            float sm, cm;  sincosf(-0.5f * (phi - omega), &sm, &cm);  // em = cm + i sm
            // U00 = ep*ct; U01 = -conj(em)*st; U10 = em*st; U11 = conj(ep)*ct
            const float u00r =  cp * ct, u00i =  sp * ct;
            const float u01r = -cm * st, u01i =  sm * st;
            const float u10r =  cm * st, u10i =  sm * st;
            const float u11r =  cp * ct, u11i = -sp * ct;

            const int post = 1 << (NW - 1 - w);
            #pragma unroll
            for (int k = 0; k < (NS / 2) / BLOCK; ++k) {
                int p  = t + k * BLOCK;
                int i0 = insert0(p, post);
                int i1 = i0 + post;
                float r0 = sre[i0], m0 = sim[i0];
                float r1 = sre[i1], m1 = sim[i1];
                sre[i0] = u00r * r0 - u00i * m0 + u01r * r1 - u01i * m1;
                sim[i0] = u00r * m0 + u00i * r0 + u01r * m1 + u01i * r1;
                sre[i1] = u10r * r0 - u10i * m0 + u11r * r1 - u11i * m1;
                sim[i1] = u10r * m0 + u10i * r0 + u11r * m1 + u11i * r1;
            }
            __syncthreads();
        }

        // CNOT ring with range r = (l % (NW-1)) + 1
        const int rr = (l % (NW - 1)) + 1;
        for (int w = 0; w < NW; ++w) {
            const int tgt   = (w + rr) % NW;
            const int cmask = 1 << (NW - 1 - w);
            const int tmask = 1 << (NW - 1 - tgt);
            const int lo = cmask < tmask ? cmask : tmask;
            const int hi = cmask < tmask ? tmask : cmask;
            #pragma unroll
            for (int k = 0; k < (NS / 4) / BLOCK; ++k) {
                int p = t + k * BLOCK;
                // index with ctrl-bit=1, tgt-bit=0; partner flips tgt bit
                int i = insert0(insert0(p, lo), hi) | cmask;
                int j = i | tmask;
                float r = sre[i], m = sim[i];
                sre[i] = sre[j];  sim[i] = sim[j];
                sre[j] = r;       sim[j] = m;
            }
            __syncthreads();
        }
    }

    // ---- probs -> PauliZ expvals -> head, fused ----
    float hwreg[NW];
    #pragma unroll
    for (int w = 0; w < NW; ++w) hwreg[w] = hw[w];

    float acc = 0.0f;
    #pragma unroll
    for (int k = 0; k < NS / BLOCK; ++k) {
        int i = t + k * BLOCK;
        float pr = sre[i] * sre[i] + sim[i] * sim[i];
        float zs = 0.0f;
        #pragma unroll
        for (int w = 0; w < NW; ++w)
            zs += ((i >> (NW - 1 - w)) & 1) ? -hwreg[w] : hwreg[w];
        acc += pr * zs;
    }

    #pragma unroll
    for (int off = 32; off > 0; off >>= 1)
        acc += __shfl_down(acc, off, 64);
    if ((t & 63) == 0) wavesum[t >> 6] = acc;
    __syncthreads();
    if (t == 0)
        out[b] = wavesum[0] + wavesum[1] + wavesum[2] + wavesum[3] + hb[0];
}

extern "C" void kernel_launch(void* const* d_in, const int* in_sizes, int n_in,
                              void* d_out, int out_size, void* d_ws, size_t ws_size,
                              hipStream_t stream) {
    const float* x   = (const float*)d_in[0];
    const float* var = (const float*)d_in[1];
    const float* hw  = (const float*)d_in[2];
    const float* hb  = (const float*)d_in[3];
    float* out = (float*)d_out;
    qnn_kernel<<<out_size, BLOCK, 0, stream>>>(x, var, hw, hb, out);
}

// Round 2
// 33.313 us; speedup vs baseline: 1.8226x; 1.8226x over previous
//
#include <hip/hip_runtime.h>

constexpr int NW = 12;
constexpr int BTHREADS = 256;   // 4 waves; state bits: [wave:2][lane:6][local:4]

struct C2 { float u00r,u00i,u01r,u01i,u10r,u10i,u11r,u11i; };
struct St { float re[16]; float im[16]; };

__device__ __forceinline__ float shx(float v, int m) { return __shfl_xor(v, m, 64); }

// ---- single-qubit gate on a LOCAL bit (pure registers) ----
template<int LM>
__device__ __forceinline__ void gate_local(St& s, const C2& u) {
    #pragma unroll
    for (int j0 = 0; j0 < 16; ++j0) {
        if (j0 & LM) continue;
        const int j1 = j0 | LM;
        float r0=s.re[j0], m0=s.im[j0], r1=s.re[j1], m1=s.im[j1];
        s.re[j0] = u.u00r*r0 - u.u00i*m0 + u.u01r*r1 - u.u01i*m1;
        s.im[j0] = u.u00r*m0 + u.u00i*r0 + u.u01r*m1 + u.u01i*r1;
        s.re[j1] = u.u10r*r0 - u.u10i*m0 + u.u11r*r1 - u.u11i*m1;
        s.im[j1] = u.u10r*m0 + u.u10i*r0 + u.u11r*m1 + u.u11i*r1;
    }
}

// ---- single-qubit gate on a LANE bit (shfl_xor exchange) ----
template<int LMASK>
__device__ __forceinline__ void gate_lane(St& s, const C2& u, int lane) {
    const bool b = (lane & LMASK) != 0;
    const float uar = b ? u.u11r : u.u00r;
    const float uai = b ? u.u11i : u.u00i;
    const float ubr = b ? u.u10r : u.u01r;
    const float ubi = b ? u.u10i : u.u01i;
    #pragma unroll
    for (int j = 0; j < 16; ++j) {
        float pr = shx(s.re[j], LMASK);
        float pi = shx(s.im[j], LMASK);
        float r = s.re[j], m = s.im[j];
        s.re[j] = uar*r - uai*m + ubr*pr - ubi*pi;
        s.im[j] = uar*m + uai*r + ubr*pi + ubi*pr;
    }
}

// ---- single-qubit gate on a WAVE bit (LDS exchange, conflict-free [j][t] layout) ----
template<int WMASK>
__device__ __forceinline__ void gate_wave(St& s, const C2& u, int t, int wid,
                                          float* bre, float* bim) {
    #pragma unroll
    for (int j = 0; j < 16; ++j) { bre[j*BTHREADS + t] = s.re[j]; bim[j*BTHREADS + t] = s.im[j]; }
    __syncthreads();
    const int pt = t ^ (WMASK << 6);
    const bool b = (wid & WMASK) != 0;
    const float uar = b ? u.u11r : u.u00r;
    const float uai = b ? u.u11i : u.u00i;
    const float ubr = b ? u.u10r : u.u01r;
    const float ubi = b ? u.u10i : u.u01i;
    #pragma unroll
    for (int j = 0; j < 16; ++j) {
        float pr = bre[j*BTHREADS + pt], pi = bim[j*BTHREADS + pt];
        float r = s.re[j], m = s.im[j];
        s.re[j] = uar*r - uai*m + ubr*pr - ubi*pi;
        s.im[j] = uar*m + uai*r + ubr*pi + ubi*pr;
    }
    __syncthreads();
}

// ---- CNOT variants (ctrl class × tgt class) ----
template<int CM, int TM>    // ctrl local, tgt local: register swap where ctrl=1
__device__ __forceinline__ void cnot_local_local(St& s) {
    #pragma unroll
    for (int j0 = 0; j0 < 16; ++j0) {
        if ((j0 & TM) || !(j0 & CM)) continue;
        const int j1 = j0 | TM;
        float r = s.re[j0]; s.re[j0] = s.re[j1]; s.re[j1] = r;
        float m = s.im[j0]; s.im[j0] = s.im[j1]; s.im[j1] = m;
    }
}

template<int CL, int TM>    // ctrl lane, tgt local: predicated in-thread swap
__device__ __forceinline__ void cnot_lane_local(St& s, int lane) {
    const bool c = (lane & CL) != 0;
    #pragma unroll
    for (int j0 = 0; j0 < 16; ++j0) {
        if (j0 & TM) continue;
        const int j1 = j0 | TM;
        float a = s.re[j0], bb = s.re[j1];
        s.re[j0] = c ? bb : a;  s.re[j1] = c ? a : bb;
        float ai = s.im[j0], bi = s.im[j1];
        s.im[j0] = c ? bi : ai; s.im[j1] = c ? ai : bi;
    }
}

template<int CL, int TL>    // ctrl lane, tgt lane: shuffle + select
__device__ __forceinline__ void cnot_lane_lane(St& s, int lane) {
    const bool c = (lane & CL) != 0;
    #pragma unroll
    for (int j = 0; j < 16; ++j) {
        float pr = shx(s.re[j], TL), pi = shx(s.im[j], TL);
        s.re[j] = c ? pr : s.re[j];
        s.im[j] = c ? pi : s.im[j];
    }
}

template<int CM, int TL>    // ctrl local, tgt lane: shuffle only ctrl=1 amps (half the shuffles)
__device__ __forceinline__ void cnot_local_lane(St& s) {
    #pragma unroll
    for (int j = 0; j < 16; ++j) {
        if (!(j & CM)) continue;
        s.re[j] = shx(s.re[j], TL);
        s.im[j] = shx(s.im[j], TL);
    }
}

template<int CW, int TL>    // ctrl wave, tgt lane: wave-uniform branch + shuffle
__device__ __forceinline__ void cnot_wave_lane(St& s, int wid) {
    if (wid & CW) {
        #pragma unroll
        for (int j = 0; j < 16; ++j) {
            s.re[j] = shx(s.re[j], TL);
            s.im[j] = shx(s.im[j], TL);
        }
    }
}

template<int CM, int WM>    // ctrl local, tgt wave: LDS exchange of ctrl=1 amps
__device__ __forceinline__ void cnot_local_wave(St& s, int t, float* bre, float* bim) {
    #pragma unroll
    for (int j = 0; j < 16; ++j) {
        if (!(j & CM)) continue;
        bre[j*BTHREADS + t] = s.re[j]; bim[j*BTHREADS + t] = s.im[j];
    }
    __syncthreads();
    const int pt = t ^ (WM << 6);
    #pragma unroll
    for (int j = 0; j < 16; ++j) {
        if (!(j & CM)) continue;
        s.re[j] = bre[j*BTHREADS + pt]; s.im[j] = bim[j*BTHREADS + pt];
    }
    __syncthreads();
}

template<int CW, int WM>    // ctrl wave, tgt wave: only ctrl waves exchange
__device__ __forceinline__ void cnot_wave_wave(St& s, int t, int wid, float* bre, float* bim) {
    if (wid & CW) {
        #pragma unroll
        for (int j = 0; j < 16; ++j) { bre[j*BTHREADS+t] = s.re[j]; bim[j*BTHREADS+t] = s.im[j]; }
    }
    __syncthreads();
    if (wid & CW) {
        const int pt = t ^ (WM << 6);
        #pragma unroll
        for (int j = 0; j < 16; ++j) { s.re[j] = bre[j*BTHREADS+pt]; s.im[j] = bim[j*BTHREADS+pt]; }
    }
    __syncthreads();
}

__global__ __launch_bounds__(BTHREADS)
void qnn_kernel(const float* __restrict__ x, const float* __restrict__ var,
                const float* __restrict__ hw, const float* __restrict__ hb,
                float* __restrict__ out)
{
    __shared__ float bre[4096];
    __shared__ float bim[4096];
    __shared__ float rotu[24][8];
    __shared__ float sxc[12], sxs[12];
    __shared__ float wavesum[4];

    const int b    = blockIdx.x;
    const int t    = threadIdx.x;
    const int lane = t & 63;
    const int wid  = t >> 6;

    // per-block precompute: per-wire sin/cos of x, and the 24 shared Rot matrices
    if (t < 12) {
        float sn, cs; sincosf(0.5f * x[b*NW + t], &sn, &cs);
        sxs[t] = sn; sxc[t] = cs;
    }
    if (t < 24) {
        const float phi   = var[t*3+0];
        const float theta = var[t*3+1];
        const float omega = var[t*3+2];
        float st, ct; sincosf(0.5f*theta, &st, &ct);
        float sp, cp; sincosf(-0.5f*(phi+omega), &sp, &cp);
        float sm, cm; sincosf(-0.5f*(phi-omega), &sm, &cm);
        rotu[t][0] =  cp*ct; rotu[t][1] =  sp*ct;   // u00
        rotu[t][2] = -cm*st; rotu[t][3] =  sm*st;   // u01
        rotu[t][4] =  cm*st; rotu[t][5] =  sm*st;   // u10
        rotu[t][6] =  cp*ct; rotu[t][7] = -sp*ct;   // u11
    }
    __syncthreads();

    // ---- product-state init: amp(i) = prod_w (bit_w ? s_w : c_w), i = t*16 + j ----
    St s;
    float F = 1.0f;
    #pragma unroll
    for (int w = 0; w < 8; ++w)
        F *= ((t >> (7 - w)) & 1) ? sxs[w] : sxc[w];
    #pragma unroll
    for (int j = 0; j < 16; ++j) {
        float v = F;
        v *= (j & 8) ? sxs[8]  : sxc[8];
        v *= (j & 4) ? sxs[9]  : sxc[9];
        v *= (j & 2) ? sxs[10] : sxc[10];
        v *= (j & 1) ? sxs[11] : sxc[11];
        s.re[j] = v; s.im[j] = 0.0f;
    }

    auto ld = [&](int g) -> C2 {
        C2 u;
        u.u00r = rotu[g][0]; u.u00i = rotu[g][1];
        u.u01r = rotu[g][2]; u.u01i = rotu[g][3];
        u.u10r = rotu[g][4]; u.u10i = rotu[g][5];
        u.u11r = rotu[g][6]; u.u11i = rotu[g][7];
        return u;
    };

    #define ROT_SWEEP(base) \
        { C2 u = ld(base+0);  gate_wave<2>(s, u, t, wid, bre, bim); } \
        { C2 u = ld(base+1);  gate_wave<1>(s, u, t, wid, bre, bim); } \
        { C2 u = ld(base+2);  gate_lane<32>(s, u, lane); } \
        { C2 u = ld(base+3);  gate_lane<16>(s, u, lane); } \
        { C2 u = ld(base+4);  gate_lane<8>(s, u, lane); }  \
        { C2 u = ld(base+5);  gate_lane<4>(s, u, lane); }  \
        { C2 u = ld(base+6);  gate_lane<2>(s, u, lane); }  \
        { C2 u = ld(base+7);  gate_lane<1>(s, u, lane); }  \
        { C2 u = ld(base+8);  gate_local<8>(s, u); } \
        { C2 u = ld(base+9);  gate_local<4>(s, u); } \
        { C2 u = ld(base+10); gate_local<2>(s, u); } \
        { C2 u = ld(base+11); gate_local<1>(s, u); }

    // ================= layer 0 =================
    ROT_SWEEP(0)
    // CNOT ring r=1, in wire order (0,1)(1,2)...(11,0)
    cnot_wave_wave<2,1>(s, t, wid, bre, bim);   // (0,1)
    cnot_wave_lane<1,32>(s, wid);               // (1,2)
    cnot_lane_lane<32,16>(s, lane);             // (2,3)
    cnot_lane_lane<16,8>(s, lane);              // (3,4)
    cnot_lane_lane<8,4>(s, lane);               // (4,5)
    cnot_lane_lane<4,2>(s, lane);               // (5,6)
    cnot_lane_lane<2,1>(s, lane);               // (6,7)
    cnot_lane_local<1,8>(s, lane);              // (7,8)
    cnot_local_local<8,4>(s);                   // (8,9)
    cnot_local_local<4,2>(s);                   // (9,10)
    cnot_local_local<2,1>(s);                   // (10,11)
    cnot_local_wave<1,2>(s, t, bre, bim);       // (11,0)

    // ================= layer 1 =================
    ROT_SWEEP(12)
    // CNOT ring r=2: (0,2)(1,3)...(11,1)
    cnot_wave_lane<2,32>(s, wid);               // (0,2)
    cnot_wave_lane<1,16>(s, wid);               // (1,3)
    cnot_lane_lane<32,8>(s, lane);              // (2,4)
    cnot_lane_lane<16,4>(s, lane);              // (3,5)
    cnot_lane_lane<8,2>(s, lane);               // (4,6)
    cnot_lane_lane<4,1>(s, lane);               // (5,7)
    cnot_lane_local<2,8>(s, lane);              // (6,8)
    cnot_lane_local<1,4>(s, lane);              // (7,9)
    cnot_local_local<8,2>(s);                   // (8,10)
    cnot_local_local<4,1>(s);                   // (9,11)
    cnot_local_wave<2,2>(s, t, bre, bim);       // (10,0)
    cnot_local_wave<1,1>(s, t, bre, bim);       // (11,1)

    #undef ROT_SWEEP

    // ---- probs -> Z expvals -> head, fused ----
    float hwreg[NW];
    #pragma unroll
    for (int w = 0; w < NW; ++w) hwreg[w] = hw[w];
    float zhi = 0.0f;
    #pragma unroll
    for (int w = 0; w < 8; ++w)
        zhi += ((t >> (7 - w)) & 1) ? -hwreg[w] : hwreg[w];
    float acc = 0.0f;
    #pragma unroll
    for (int j = 0; j < 16; ++j) {
        float pr = s.re[j]*s.re[j] + s.im[j]*s.im[j];
        float z = zhi;
        z += (j & 8) ? -hwreg[8]  : hwreg[8];
        z += (j & 4) ? -hwreg[9]  : hwreg[9];
        z += (j & 2) ? -hwreg[10] : hwreg[10];
        z += (j & 1) ? -hwreg[11] : hwreg[11];
        acc += pr * z;
    }
    #pragma unroll
    for (int off = 32; off > 0; off >>= 1) acc += __shfl_down(acc, off, 64);
    if (lane == 0) wavesum[wid] = acc;
    __syncthreads();
    if (t == 0) out[b] = wavesum[0] + wavesum[1] + wavesum[2] + wavesum[3] + hb[0];
}

extern "C" void kernel_launch(void* const* d_in, const int* in_sizes, int n_in,
                              void* d_out, int out_size, void* d_ws, size_t ws_size,
                              hipStream_t stream) {
    const float* x   = (const float*)d_in[0];
    const float* var = (const float*)d_in[1];
    const float* hw  = (const float*)d_in[2];
    const float* hb  = (const float*)d_in[3];
    float* out = (float*)d_out;
    qnn_kernel<<<out_size, BTHREADS, 0, stream>>>(x, var, hw, hb, out);
}